// Round 10
// baseline (103.762 us; speedup 1.0000x reference)
//
#include <hip/hip_runtime.h>
#include <math.h>

#define BB 16
#define NN 4096            // N == M == 4096
#define KK 128
#define CT 128             // cols per block (2 packed groups of 64)
#define RPT 16             // rows per thread -> block covers all 4096 rows
#define TPB 256
#define NCTILE (NN / CT)   // 32
#define W_POINT  1.0f
#define W_COEFF  0.5f
#define W_AFFINE 0.5f

typedef float f2 __attribute__((ext_vector_type(2)));
typedef float f4 __attribute__((ext_vector_type(4)));

__device__ inline float min3f(float a, float b, float c) {
    float r;
    asm("v_min3_f32 %0, %1, %2, %3" : "=v"(r) : "v"(a), "v"(b), "v"(c));
    return r;
}
__device__ inline f2 pk_add(f2 a, f2 b) {
    f2 r;
    asm("v_pk_add_f32 %0, %1, %2" : "=v"(r) : "v"(a), "v"(b));
    return r;
}
__device__ inline f2 pk_fma(f2 a, f2 b, f2 c) {
    f2 r;
    asm("v_pk_fma_f32 %0, %1, %2, %3" : "=v"(r) : "v"(a), "v"(b), "v"(c));
    return r;
}

__device__ inline void compute_affine(const float* __restrict__ aff,
                                      float R[9], float sc[3], float tr[3]) {
    float ax = aff[0], ay = aff[1], az = aff[2];
    tr[0] = aff[3]; tr[1] = aff[4]; tr[2] = aff[5];
    sc[0] = aff[6]; sc[1] = aff[7]; sc[2] = aff[8];
    float cx = cosf(ax), sx = sinf(ax);
    float cy = cosf(ay), sy = sinf(ay);
    float cz = cosf(az), sz = sinf(az);
    R[0] = cy * cz;                 R[1] = -cy * sz;                R[2] = sy;
    R[3] = cx * sz + sx * sy * cz;  R[4] = cx * cz - sx * sy * sz;  R[5] = -sx * cy;
    R[6] = sx * sz - cx * sy * cz;  R[7] = sx * cz + cx * sy * sz;  R[8] = cx * cy;
}

__device__ inline void apply_affine(const float R[9], const float sc[3], const float tr[3],
                                    float x, float y, float z,
                                    float& ox, float& oy, float& oz) {
    ox = fmaf(fmaf(x, R[0], fmaf(y, R[3], z * R[6])), sc[0], tr[0]);
    oy = fmaf(fmaf(x, R[1], fmaf(y, R[4], z * R[7])), sc[1], tr[1]);
    oz = fmaf(fmaf(x, R[2], fmaf(y, R[5], z * R[8])), sc[2], tr[2]);
}

// One-pass Chamfer, LDS-pipe-optimized. Block = ALL 4096 rows x 128 cols of
// one batch's d2 tile (pair evaluated ONCE). grid = 16*32 = 512 blocks.
// LDS per slot s: A[s]={x_s,x_{s+64},y_s,y_{s+64}}, B[s]={z_s,z_{s+64},w_s,w_{s+64}}
// -> per iter only 2 ds_read_b128 + 2 ds_bpermute (was 6 DS ops for half the
// pairs). Rows (16/thread) in registers as packed f2 broadcasts. Row-mins
// thread-local; col-mins rotate one lane/iter (ds_bpermute). No atomics:
//   rp[(b*32+ctile)*NN + row]   row-partial mins (min over 32 ctiles later)
//   cp[(b*4+wid)*NN + col]      per-wave col-partials (min over 4 later)
__global__ __launch_bounds__(TPB) void chamfer_kernel(
        const float* __restrict__ pred_shape,
        const float* __restrict__ targ_shape,
        const float* __restrict__ targ_affine,
        float* __restrict__ rp,
        float* __restrict__ cp) {
    __shared__ float ldsA[64 * 4];   // 1 KiB
    __shared__ float ldsB[64 * 4];   // 1 KiB

    const int bx    = blockIdx.x;
    const int ctile = bx & (NCTILE - 1);
    const int b     = bx >> 5;
    const int tid   = threadIdx.x;
    const int lane  = tid & 63;
    const int wid   = tid >> 6;

    // ---- stage 128 transformed target cols ----
    if (tid < CT) {
        float R[9], sc[3], tr[3];
        compute_affine(targ_affine + b * 9, R, sc, tr);
        const int s = tid & 63, h = tid >> 6;     // col = ctile*128 + s + 64*h
        const float* t = targ_shape + ((size_t)b * NN + ctile * CT + tid) * 3;
        float mx, my, mz;
        apply_affine(R, sc, tr, t[0], t[1], t[2], mx, my, mz);
        ldsA[s * 4 + 0 + h] = mx;
        ldsA[s * 4 + 2 + h] = my;
        ldsB[s * 4 + 0 + h] = mz;
        ldsB[s * 4 + 2 + h] = fmaf(mx, mx, fmaf(my, my, mz * mz));
    }

    // ---- load 16 pred rows per thread; broadcast constants as pairs ----
    f2 axp[RPT], ayp[RPT], azp[RPT], q2p[RPT];
    float rmin[RPT];
    #pragma unroll
    for (int k = 0; k < RPT; ++k) {
        const float* p = pred_shape + ((size_t)b * NN + k * TPB + tid) * 3;
        float x = p[0], y = p[1], z = p[2];
        float q2 = fmaf(x, x, fmaf(y, y, z * z));
        axp[k] = (f2){-2.0f * x, -2.0f * x};
        ayp[k] = (f2){-2.0f * y, -2.0f * y};
        azp[k] = (f2){-2.0f * z, -2.0f * z};
        q2p[k] = (f2){q2, q2};
        rmin[k] = 1e30f;
    }
    __syncthreads();

    // ---- rotating scan: iter i, lane l handles pair slot (l+i)&63 ----
    const f4* baseA = (const f4*)ldsA;
    const f4* baseB = (const f4*)ldsB;
    f2 cr = (f2){1e30f, 1e30f};              // rotating col-min accumulators
    const int rot = ((lane + 1) & 63) << 2;
    int idx = lane;
    for (int i = 0; i < 64; ++i) {
        f4 va = baseA[idx];
        f4 vb = baseB[idx];
        f2 x01 = __builtin_shufflevector(va, va, 0, 1);
        f2 y01 = __builtin_shufflevector(va, va, 2, 3);
        f2 z01 = __builtin_shufflevector(vb, vb, 0, 1);
        f2 w01 = __builtin_shufflevector(vb, vb, 2, 3);
        float cA, cB;
        #pragma unroll
        for (int k = 0; k < RPT; k += 2) {
            f2 s0 = pk_add(q2p[k], w01);
            f2 e0 = pk_fma(azp[k], z01, s0);
            e0 = pk_fma(ayp[k], y01, e0);
            e0 = pk_fma(axp[k], x01, e0);
            f2 s1 = pk_add(q2p[k + 1], w01);
            f2 e1 = pk_fma(azp[k + 1], z01, s1);
            e1 = pk_fma(ayp[k + 1], y01, e1);
            e1 = pk_fma(axp[k + 1], x01, e1);
            rmin[k]     = min3f(rmin[k],     e0[0], e0[1]);
            rmin[k + 1] = min3f(rmin[k + 1], e1[0], e1[1]);
            if (k == 0) {
                cA = min3f(e0[0], e1[0], cr[0]);     // seed with rotating acc
                cB = min3f(e0[1], e1[1], cr[1]);
            } else {
                cA = min3f(cA, e0[0], e1[0]);
                cB = min3f(cB, e0[1], e1[1]);
            }
        }
        // rotate down one lane: new[l] = old[(l+1)&63]
        cr[0] = __int_as_float(__builtin_amdgcn_ds_bpermute(rot, __float_as_int(cA)));
        cr[1] = __int_as_float(__builtin_amdgcn_ds_bpermute(rot, __float_as_int(cB)));
        idx = (idx + 1) & 63;
    }
    // after 64 iters + rotates, lane l holds slot l (cols ctile*128+l, +64)

    // ---- plain stores of owned partials (clamp commutes with min) ----
    #pragma unroll
    for (int k = 0; k < RPT; ++k)
        rp[((size_t)b * NCTILE + ctile) * NN + k * TPB + tid] =
            fmaxf(rmin[k], 0.0f);
    {
        float* cbase = cp + ((size_t)b * 4 + wid) * NN + ctile * CT;
        cbase[lane]      = fmaxf(cr[0], 0.0f);
        cbase[64 + lane] = fmaxf(cr[1], 0.0f);
    }
}

// 512 blocks, all loads lane-coalesced.
// Blocks 0..255  (b = j>>4): rows. row = (j&15)*256+tid; min over 32 ctile
//   slabs rp[(b*32+c)*NN + row].
// Blocks 256..511: cols. col = (jj&15)*256+tid; min over 4 wave slices
//   cp[(b*4+s)*NN + col].
__global__ __launch_bounds__(TPB) void reduce_kernel(
        const float* __restrict__ rp, const float* __restrict__ cp,
        float* __restrict__ partials) {
    const int j   = blockIdx.x;
    const int tid = threadIdx.x;
    float m;
    if (j < 256) {
        const int b = j >> 4, row = (j & 15) * TPB + tid;
        const float* basep = rp + (size_t)b * NCTILE * NN + row;
        m = basep[0];
        #pragma unroll
        for (int c = 1; c < NCTILE; ++c) m = fminf(m, basep[(size_t)c * NN]);
    } else {
        const int jj = j - 256;
        const int b = jj >> 4, col = (jj & 15) * TPB + tid;
        const float* basep = cp + (size_t)b * 4 * NN + col;
        m = basep[0];
        #pragma unroll
        for (int s = 1; s < 4; ++s) m = fminf(m, basep[(size_t)s * NN]);
    }
    #pragma unroll
    for (int off = 32; off > 0; off >>= 1) m += __shfl_down(m, off);
    __shared__ float sps[4];
    if ((tid & 63) == 0) sps[tid >> 6] = m;
    __syncthreads();
    if (tid == 0) partials[j] = sps[0] + sps[1] + sps[2] + sps[3];
}

__global__ __launch_bounds__(TPB) void final_combine(
        const float* __restrict__ partials,
        const float* __restrict__ pred_w,  const float* __restrict__ targ_w,
        const float* __restrict__ pred_aff, const float* __restrict__ targ_aff,
        float* __restrict__ out) {
    const int tid = threadIdx.x;
    float ps = partials[tid] + partials[256 + tid];
    float cs = 0.0f;
    #pragma unroll
    for (int r = 0; r < (BB * KK) / TPB; ++r) {   // 2048 floats
        float d = pred_w[r * TPB + tid] - targ_w[r * TPB + tid];
        cs = fmaf(d, d, cs);
    }
    float as = 0.0f;
    if (tid < BB * 9) {
        float d = pred_aff[tid] - targ_aff[tid];
        as = d * d;
    }
    #pragma unroll
    for (int off = 32; off > 0; off >>= 1) {
        ps += __shfl_down(ps, off);
        cs += __shfl_down(cs, off);
        as += __shfl_down(as, off);
    }
    __shared__ float sps[4], scs[4], sas[4];
    const int wid = tid >> 6;
    if ((tid & 63) == 0) { sps[wid] = ps; scs[wid] = cs; sas[wid] = as; }
    __syncthreads();
    if (tid == 0) {
        float p = sps[0] + sps[1] + sps[2] + sps[3];
        float c = scs[0] + scs[1] + scs[2] + scs[3];
        float a = sas[0] + sas[1] + sas[2] + sas[3];
        float point  = p / (float)(BB * NN);   // row-min and col-min share denom
        float coeff  = c / (float)(BB * KK);
        float affine = a / (float)(BB * 9);
        out[0] = W_POINT * point + W_COEFF * coeff + W_AFFINE * affine;
        out[1] = point;
        out[2] = coeff;
        out[3] = affine;
    }
}

extern "C" void kernel_launch(void* const* d_in, const int* in_sizes, int n_in,
                              void* d_out, int out_size, void* d_ws, size_t ws_size,
                              hipStream_t stream) {
    const float* pred_shape = (const float*)d_in[0];
    const float* pred_w     = (const float*)d_in[1];
    const float* pred_aff   = (const float*)d_in[2];
    const float* targ_shape = (const float*)d_in[3];
    const float* targ_w     = (const float*)d_in[4];
    const float* targ_aff   = (const float*)d_in[5];
    float* out = (float*)d_out;

    // ws layout (all fully overwritten every call; no init needed):
    float* rp = (float*)d_ws;                              // 16*32*4096 = 8 MiB
    float* cp = rp + (size_t)BB * NCTILE * NN;             // 16*4*4096  = 1 MiB
    float* partials = cp + (size_t)BB * 4 * NN;            // 512 floats

    chamfer_kernel<<<dim3(BB * NCTILE), TPB, 0, stream>>>(
        pred_shape, targ_shape, targ_aff, rp, cp);
    reduce_kernel<<<512, TPB, 0, stream>>>(rp, cp, partials);
    final_combine<<<1, TPB, 0, stream>>>(partials, pred_w, targ_w,
                                         pred_aff, targ_aff, out);
}

// Round 11
// 101.474 us; speedup vs baseline: 1.0226x; 1.0226x over previous
//
#include <hip/hip_runtime.h>
#include <math.h>

#define BB 16
#define NN 4096            // N == M == 4096
#define KK 128
#define RT 2048            // rows per block (8 per thread)
#define CT 128             // cols per block (2 packed groups of 64)
#define RPT 8              // rows per thread
#define TPB 256
#define NRTILE (NN / RT)   // 2
#define NCTILE (NN / CT)   // 32
#define W_POINT  1.0f
#define W_COEFF  0.5f
#define W_AFFINE 0.5f

typedef float f2 __attribute__((ext_vector_type(2)));
typedef float f4 __attribute__((ext_vector_type(4)));

__device__ inline float min3f(float a, float b, float c) {
    float r;
    asm("v_min3_f32 %0, %1, %2, %3" : "=v"(r) : "v"(a), "v"(b), "v"(c));
    return r;
}
__device__ inline f2 pk_add(f2 a, f2 b) {
    f2 r;
    asm("v_pk_add_f32 %0, %1, %2" : "=v"(r) : "v"(a), "v"(b));
    return r;
}
__device__ inline f2 pk_fma(f2 a, f2 b, f2 c) {
    f2 r;
    asm("v_pk_fma_f32 %0, %1, %2, %3" : "=v"(r) : "v"(a), "v"(b), "v"(c));
    return r;
}

__device__ inline void compute_affine(const float* __restrict__ aff,
                                      float R[9], float sc[3], float tr[3]) {
    float ax = aff[0], ay = aff[1], az = aff[2];
    tr[0] = aff[3]; tr[1] = aff[4]; tr[2] = aff[5];
    sc[0] = aff[6]; sc[1] = aff[7]; sc[2] = aff[8];
    float cx = cosf(ax), sx = sinf(ax);
    float cy = cosf(ay), sy = sinf(ay);
    float cz = cosf(az), sz = sinf(az);
    R[0] = cy * cz;                 R[1] = -cy * sz;                R[2] = sy;
    R[3] = cx * sz + sx * sy * cz;  R[4] = cx * cz - sx * sy * sz;  R[5] = -sx * cy;
    R[6] = sx * sz - cx * sy * cz;  R[7] = sx * cz + cx * sy * sz;  R[8] = cx * cy;
}

__device__ inline void apply_affine(const float R[9], const float sc[3], const float tr[3],
                                    float x, float y, float z,
                                    float& ox, float& oy, float& oz) {
    ox = fmaf(fmaf(x, R[0], fmaf(y, R[3], z * R[6])), sc[0], tr[0]);
    oy = fmaf(fmaf(x, R[1], fmaf(y, R[4], z * R[7])), sc[1], tr[1]);
    oz = fmaf(fmaf(x, R[2], fmaf(y, R[5], z * R[8])), sc[2], tr[2]);
}

// One-pass Chamfer. Block = 2048 rows x 128 cols of one batch's d2 tile
// (pair evaluated ONCE). grid = 16*2*32 = 1024 blocks -> 4 blocks/CU =
// 4 waves/SIMD (latency hiding) while DS stays amortized (f4 layout:
// 2 ds_read_b128 + 2 ds_bpermute per iter). v_pk_* is HALF-RATE on gfx950
// (no dual-issue fp32) so VALU floor ~0.17 cyc/pair; DS ~15us/CU parallel.
// Row-mins thread-local; col-mins rotate one lane/iter. No atomics:
//   rp[(b*32+ctile)*NN + row]          row-partials (min over 32 later)
//   cp[((b*2+rtile)*4+wid)*NN + col]   per-wave col-partials (min over 8)
__global__ __launch_bounds__(TPB, 4) void chamfer_kernel(
        const float* __restrict__ pred_shape,
        const float* __restrict__ targ_shape,
        const float* __restrict__ targ_affine,
        float* __restrict__ rp,
        float* __restrict__ cp) {
    __shared__ float ldsA[64 * 4];   // {x_s, x_{s+64}, y_s, y_{s+64}} per slot
    __shared__ float ldsB[64 * 4];   // {z_s, z_{s+64}, w_s, w_{s+64}} per slot

    const int bx    = blockIdx.x;
    const int ctile = bx & (NCTILE - 1);
    const int rtile = (bx >> 5) & (NRTILE - 1);
    const int b     = bx >> 6;
    const int tid   = threadIdx.x;
    const int lane  = tid & 63;
    const int wid   = tid >> 6;

    // ---- stage 128 transformed target cols ----
    if (tid < CT) {
        float R[9], sc[3], tr[3];
        compute_affine(targ_affine + b * 9, R, sc, tr);
        const int s = tid & 63, h = tid >> 6;     // col = ctile*128 + s + 64*h
        const float* t = targ_shape + ((size_t)b * NN + ctile * CT + tid) * 3;
        float mx, my, mz;
        apply_affine(R, sc, tr, t[0], t[1], t[2], mx, my, mz);
        ldsA[s * 4 + 0 + h] = mx;
        ldsA[s * 4 + 2 + h] = my;
        ldsB[s * 4 + 0 + h] = mz;
        ldsB[s * 4 + 2 + h] = fmaf(mx, mx, fmaf(my, my, mz * mz));
    }

    // ---- load 8 pred rows per thread; broadcast constants as pairs ----
    const int rowbase = rtile * RT;
    f2 axp[RPT], ayp[RPT], azp[RPT], q2p[RPT];
    float rmin[RPT];
    #pragma unroll
    for (int k = 0; k < RPT; ++k) {
        const float* p = pred_shape + ((size_t)b * NN + rowbase + k * TPB + tid) * 3;
        float x = p[0], y = p[1], z = p[2];
        float q2 = fmaf(x, x, fmaf(y, y, z * z));
        axp[k] = (f2){-2.0f * x, -2.0f * x};
        ayp[k] = (f2){-2.0f * y, -2.0f * y};
        azp[k] = (f2){-2.0f * z, -2.0f * z};
        q2p[k] = (f2){q2, q2};
        rmin[k] = 1e30f;
    }
    __syncthreads();

    // ---- rotating scan: iter i, lane l handles pair slot (l+i)&63 ----
    const f4* baseA = (const f4*)ldsA;
    const f4* baseB = (const f4*)ldsB;
    f2 cr = (f2){1e30f, 1e30f};              // rotating col-min accumulators
    const int rot = ((lane + 1) & 63) << 2;
    int idx = lane;
    for (int i = 0; i < 64; ++i) {
        f4 va = baseA[idx];
        f4 vb = baseB[idx];
        f2 x01 = __builtin_shufflevector(va, va, 0, 1);
        f2 y01 = __builtin_shufflevector(va, va, 2, 3);
        f2 z01 = __builtin_shufflevector(vb, vb, 0, 1);
        f2 w01 = __builtin_shufflevector(vb, vb, 2, 3);
        float cA, cB;
        #pragma unroll
        for (int k = 0; k < RPT; k += 2) {
            f2 s0 = pk_add(q2p[k], w01);
            f2 e0 = pk_fma(azp[k], z01, s0);
            e0 = pk_fma(ayp[k], y01, e0);
            e0 = pk_fma(axp[k], x01, e0);
            f2 s1 = pk_add(q2p[k + 1], w01);
            f2 e1 = pk_fma(azp[k + 1], z01, s1);
            e1 = pk_fma(ayp[k + 1], y01, e1);
            e1 = pk_fma(axp[k + 1], x01, e1);
            rmin[k]     = min3f(rmin[k],     e0[0], e0[1]);
            rmin[k + 1] = min3f(rmin[k + 1], e1[0], e1[1]);
            if (k == 0) {
                cA = min3f(e0[0], e1[0], cr[0]);     // seed with rotating acc
                cB = min3f(e0[1], e1[1], cr[1]);
            } else {
                cA = min3f(cA, e0[0], e1[0]);
                cB = min3f(cB, e0[1], e1[1]);
            }
        }
        // rotate down one lane: new[l] = old[(l+1)&63]
        cr[0] = __int_as_float(__builtin_amdgcn_ds_bpermute(rot, __float_as_int(cA)));
        cr[1] = __int_as_float(__builtin_amdgcn_ds_bpermute(rot, __float_as_int(cB)));
        idx = (idx + 1) & 63;
    }
    // after 64 iters + rotates, lane l holds slot l (cols ctile*128+l, +64)

    // ---- plain stores of owned partials (clamp commutes with min) ----
    #pragma unroll
    for (int k = 0; k < RPT; ++k)
        rp[((size_t)b * NCTILE + ctile) * NN + rowbase + k * TPB + tid] =
            fmaxf(rmin[k], 0.0f);
    {
        float* cbase = cp + (((size_t)b * NRTILE + rtile) * 4 + wid) * NN + ctile * CT;
        cbase[lane]      = fmaxf(cr[0], 0.0f);
        cbase[64 + lane] = fmaxf(cr[1], 0.0f);
    }
}

// 512 blocks, all loads lane-coalesced.
// Blocks 0..255  (b = j>>4): rows. row = (j&15)*256+tid; min over 32 ctile
//   slabs rp[(b*32+c)*NN + row].
// Blocks 256..511: cols. col = (jj&15)*256+tid; min over 8 slices
//   cp[(b*8+s)*NN + col].
__global__ __launch_bounds__(TPB) void reduce_kernel(
        const float* __restrict__ rp, const float* __restrict__ cp,
        float* __restrict__ partials) {
    const int j   = blockIdx.x;
    const int tid = threadIdx.x;
    float m;
    if (j < 256) {
        const int b = j >> 4, row = (j & 15) * TPB + tid;
        const float* basep = rp + (size_t)b * NCTILE * NN + row;
        m = basep[0];
        #pragma unroll
        for (int c = 1; c < NCTILE; ++c) m = fminf(m, basep[(size_t)c * NN]);
    } else {
        const int jj = j - 256;
        const int b = jj >> 4, col = (jj & 15) * TPB + tid;
        const float* basep = cp + (size_t)b * 8 * NN + col;
        m = basep[0];
        #pragma unroll
        for (int s = 1; s < 8; ++s) m = fminf(m, basep[(size_t)s * NN]);
    }
    #pragma unroll
    for (int off = 32; off > 0; off >>= 1) m += __shfl_down(m, off);
    __shared__ float sps[4];
    if ((tid & 63) == 0) sps[tid >> 6] = m;
    __syncthreads();
    if (tid == 0) partials[j] = sps[0] + sps[1] + sps[2] + sps[3];
}

__global__ __launch_bounds__(TPB) void final_combine(
        const float* __restrict__ partials,
        const float* __restrict__ pred_w,  const float* __restrict__ targ_w,
        const float* __restrict__ pred_aff, const float* __restrict__ targ_aff,
        float* __restrict__ out) {
    const int tid = threadIdx.x;
    float ps = partials[tid] + partials[256 + tid];
    float cs = 0.0f;
    #pragma unroll
    for (int r = 0; r < (BB * KK) / TPB; ++r) {   // 2048 floats
        float d = pred_w[r * TPB + tid] - targ_w[r * TPB + tid];
        cs = fmaf(d, d, cs);
    }
    float as = 0.0f;
    if (tid < BB * 9) {
        float d = pred_aff[tid] - targ_aff[tid];
        as = d * d;
    }
    #pragma unroll
    for (int off = 32; off > 0; off >>= 1) {
        ps += __shfl_down(ps, off);
        cs += __shfl_down(cs, off);
        as += __shfl_down(as, off);
    }
    __shared__ float sps[4], scs[4], sas[4];
    const int wid = tid >> 6;
    if ((tid & 63) == 0) { sps[wid] = ps; scs[wid] = cs; sas[wid] = as; }
    __syncthreads();
    if (tid == 0) {
        float p = sps[0] + sps[1] + sps[2] + sps[3];
        float c = scs[0] + scs[1] + scs[2] + scs[3];
        float a = sas[0] + sas[1] + sas[2] + sas[3];
        float point  = p / (float)(BB * NN);   // row-min and col-min share denom
        float coeff  = c / (float)(BB * KK);
        float affine = a / (float)(BB * 9);
        out[0] = W_POINT * point + W_COEFF * coeff + W_AFFINE * affine;
        out[1] = point;
        out[2] = coeff;
        out[3] = affine;
    }
}

extern "C" void kernel_launch(void* const* d_in, const int* in_sizes, int n_in,
                              void* d_out, int out_size, void* d_ws, size_t ws_size,
                              hipStream_t stream) {
    const float* pred_shape = (const float*)d_in[0];
    const float* pred_w     = (const float*)d_in[1];
    const float* pred_aff   = (const float*)d_in[2];
    const float* targ_shape = (const float*)d_in[3];
    const float* targ_w     = (const float*)d_in[4];
    const float* targ_aff   = (const float*)d_in[5];
    float* out = (float*)d_out;

    // ws layout (all fully overwritten every call; no init needed):
    float* rp = (float*)d_ws;                              // 16*32*4096 = 8 MiB
    float* cp = rp + (size_t)BB * NCTILE * NN;             // 16*8*4096  = 2 MiB
    float* partials = cp + (size_t)BB * 8 * NN;            // 512 floats

    chamfer_kernel<<<dim3(BB * NRTILE * NCTILE), TPB, 0, stream>>>(
        pred_shape, targ_shape, targ_aff, rp, cp);
    reduce_kernel<<<512, TPB, 0, stream>>>(rp, cp, partials);
    final_combine<<<1, TPB, 0, stream>>>(partials, pred_w, targ_w,
                                         pred_aff, targ_aff, out);
}